// Round 9
// baseline (513.875 us; speedup 1.0000x reference)
//
#include <hip/hip_runtime.h>
#include <hip/hip_bf16.h>
#include <cstddef>

// Problem constants (LiteFlowNetCorr): B=8, C=128, H=128, W=224, R=4
#define BN 8
#define CCH 128
#define HH 128
#define WW 224
#define ND 81            // (2R+1)^2 displacements
#define CINP1 224        // conv1 K padded: 128 (x1) + 81 (corr) + 15 zeros

typedef __attribute__((ext_vector_type(8))) short short8_t;   // 8 bf16
typedef __attribute__((ext_vector_type(4))) float float4_t;   // MFMA acc

static __device__ __forceinline__ unsigned short f2bf(float f) {
  __hip_bfloat16 h = __float2bfloat16(f);
  return *(unsigned short*)&h;
}
static __device__ __forceinline__ float bf2f(short s) {
  unsigned u = ((unsigned)(unsigned short)s) << 16;
  return __uint_as_float(u);
}

// ---------------------------------------------------------------------------
// convert_x1 (v3, LDS transpose): x1 fp32 NCHW -> A0 bf16 NHWC.
// Block = 64 px x 128 ch. Phase 1: float4 pixel-major loads (4x256B runs
// per wave, lines fully used), pack bf16 pairs -> LDS [px][cp] stride 65
// (2-way max bank aliasing). Phase 2: 4x b32 reads (2-way max) -> uint4
// chunk stores, 16 consecutive chunks/lane-group = 256B runs.
// Chunks 26,27 zeroed (ch 209..223 pad; corr fills 128..208).
// ---------------------------------------------------------------------------
__global__ __launch_bounds__(256) void convert_x1(
    const float* __restrict__ x1, uint4* __restrict__ a0q) {
  __shared__ unsigned sT[64 * 65];  // [px][cp], stride 65 dwords
  const int tid = threadIdx.x;
  const int g0 = blockIdx.x * 64;   // 64 | hw, tiles never cross batch
  const int hw = HH * WW;
  const int b = g0 / hw, px0 = g0 - b * hw;
  const float* src = x1 + (size_t)b * CCH * hw + px0;

#pragma unroll
  for (int it = 0; it < 4; ++it) {
    const int s = it * 256 + tid;
    const int pg4 = s & 15, cp = s >> 4;   // cp = channel pair 0..63
    const float4 a = *(const float4*)&src[(size_t)(2 * cp) * hw + 4 * pg4];
    const float4 c = *(const float4*)&src[(size_t)(2 * cp + 1) * hw + 4 * pg4];
    const float av[4] = {a.x, a.y, a.z, a.w};
    const float cv[4] = {c.x, c.y, c.z, c.w};
#pragma unroll
    for (int j = 0; j < 4; ++j) {
      sT[(4 * pg4 + j) * 65 + cp] =
          (unsigned)f2bf(av[j]) | ((unsigned)f2bf(cv[j]) << 16);
    }
  }
  __syncthreads();

#pragma unroll
  for (int it = 0; it < 4; ++it) {
    const int s = it * 256 + tid;
    const int chunk = s & 15, px = s >> 4;
    uint4 u;
    u.x = sT[px * 65 + 4 * chunk + 0];
    u.y = sT[px * 65 + 4 * chunk + 1];
    u.z = sT[px * 65 + 4 * chunk + 2];
    u.w = sT[px * 65 + 4 * chunk + 3];
    a0q[(size_t)(g0 + px) * 28 + chunk] = u;
  }
  if (tid < 128) {
    const int px = tid >> 1, ch = 26 + (tid & 1);
    uint4 z; z.x = z.y = z.z = z.w = 0u;
    a0q[(size_t)(g0 + px) * 28 + ch] = z;
  }
}

// ---------------------------------------------------------------------------
// convert_x2 (v3, LDS transpose): x2 fp32 NCHW -> bf16 planes
// [16 planes][B*H*W] of uint4; plane p holds channels p*8..p*8+7.
// Block = 256 px x 1 plane. Phase 1: cp = tid&3 interleave -> per-wave
// 8 runs of 256B fully-used float4 loads; LDS [px][cp] stride 5 (2-way max).
// Phase 2: 4x b32 reads (2-way) -> uint4 store, 4KB contiguous per wave.
// ---------------------------------------------------------------------------
__global__ __launch_bounds__(256) void convert_x2(
    const float* __restrict__ x2, uint4* __restrict__ x2q) {
  __shared__ unsigned sT[256 * 5];  // [px][cp], stride 5 dwords
  const int tid = threadIdx.x;
  const int p = blockIdx.y;                      // plane 0..15
  const int g0 = blockIdx.x * 256;               // 256 | hw
  const int hw = HH * WW;
  const int b = g0 / hw, px0 = g0 - b * hw;
  const float* src = x2 + ((size_t)b * CCH + p * 8) * hw + px0;

  const int cp = tid & 3, pg4 = tid >> 2;        // pg4 = 0..63
  const float4 a = *(const float4*)&src[(size_t)(2 * cp) * hw + 4 * pg4];
  const float4 c = *(const float4*)&src[(size_t)(2 * cp + 1) * hw + 4 * pg4];
  const float av[4] = {a.x, a.y, a.z, a.w};
  const float cv[4] = {c.x, c.y, c.z, c.w};
#pragma unroll
  for (int j = 0; j < 4; ++j) {
    sT[(4 * pg4 + j) * 5 + cp] =
        (unsigned)f2bf(av[j]) | ((unsigned)f2bf(cv[j]) << 16);
  }
  __syncthreads();

  uint4 u;
  u.x = sT[tid * 5 + 0];
  u.y = sT[tid * 5 + 1];
  u.z = sT[tid * 5 + 2];
  u.w = sT[tid * 5 + 3];
  x2q[(size_t)p * (BN * hw) + g0 + tid] = u;
}

// ---------------------------------------------------------------------------
// corr_mfma (v4, double-buffered sB): correlation as banded implicit GEMM.
// Valid outputs: dx = n - m in [0,8]. Two 16x16x32 bf16 MFMA N-tiles per
// 32-channel block.
//
// Grid: 1D 896 with XCD swizzle (batch = xcd, x-major within batch) for L2
// halo reuse. Block: 512 thr = 8 waves; wave w owns y rows 2w, 2w+1.
// v4: sB[2][2304] (73.7 KB, 2 blocks/CU at 147<=160 KB). ONE barrier per
// cb; cb+1's staging loads issue before cb's compute -> L2/HBM latency
// drains under the 36-MFMA + 20-ds_read block instead of under a barrier.
// use_preconv!=0: stage from bf16 planes (1 coalesced uint4 load/item).
// LDS sB[h][qs*576 + r*24 + c]: writes consecutive, B-frag reads 2-way max.
// ---------------------------------------------------------------------------
__global__ __launch_bounds__(512, 2) void corr_mfma(
    const float* __restrict__ x2,
    const uint4* __restrict__ x2q,          // bf16 planes (may alias A0)
    const uint4* __restrict__ a0q,          // x1 bf16 NHWC = chunks 0..15
    __hip_bfloat16* __restrict__ a0,        // corr out: channels 128..208
    int use_preconv) {
  __shared__ uint4 sB[2][4 * 576];  // [half][q][r*24+c]
  const int tid = threadIdx.x;
  const int lane = tid & 63, w = tid >> 6;   // 8 waves
  const int m = lane & 15, q = lane >> 4;    // MFMA operand lane split
  // XCD swizzle: 896 blocks = 8 xcd chunks of 112; batch = xcd.
  const int lin = blockIdx.x;
  const int b = lin & 7, idx = lin >> 3;
  const int x0 = (idx % 14) * 16, y0 = (idx / 14) * 16;
  const int hw = HH * WW;

  float4_t acc[2][9][2];
#pragma unroll
  for (int yy = 0; yy < 2; ++yy)
#pragma unroll
    for (int d = 0; d < 9; ++d)
#pragma unroll
      for (int t = 0; t < 2; ++t) acc[yy][d][t] = (float4_t)0.0f;

  auto stage = [&](int cb, int half) {
    for (int s = tid; s < 2304; s += 512) {
      const int qs = s / 576, rc = s - qs * 576;
      const int r = rc / 24, c = rc - r * 24;
      const int gy = y0 - 4 + r, gx = x0 - 4 + c;
      uint4 u; u.x = u.y = u.z = u.w = 0u;
      if (gy >= 0 && gy < HH && gx >= 0 && gx < WW) {
        if (use_preconv) {
          u = x2q[(size_t)(cb * 4 + qs) * (BN * hw) +
                  (size_t)(b * HH + gy) * WW + gx];
        } else {
          const float* p2 =
              x2 + (size_t)(b * CCH + cb * 32 + qs * 8) * hw + gy * WW + gx;
          unsigned rr[4];
#pragma unroll
          for (int j = 0; j < 4; ++j) {
            const float f0 = p2[(size_t)(2 * j + 0) * hw];
            const float f1 = p2[(size_t)(2 * j + 1) * hw];
            rr[j] = (unsigned)f2bf(f0) | ((unsigned)f2bf(f1) << 16);
          }
          u.x = rr[0]; u.y = rr[1]; u.z = rr[2]; u.w = rr[3];
        }
      }
      sB[half][s] = u;
    }
  };

  stage(0, 0);
  for (int cb = 0; cb < 4; ++cb) {  // 4 blocks of 32 channels
    __syncthreads();                 // half (cb&1) staged; prev reads done
    if (cb + 1 < 4) stage(cb + 1, (cb + 1) & 1);
    const int half = cb & 1;

    // --- A-fragments: this wave's two x1 rows, from A0 (bf16 NHWC) ---
    uint4 afr[2];
#pragma unroll
    for (int yy = 0; yy < 2; ++yy) {
      const int y = y0 + 2 * w + yy;
      afr[yy] = a0q[((size_t)(b * HH + y) * WW + x0 + m) * 28 + cb * 4 + q];
    }
    const short8_t af0 = *(const short8_t*)&afr[0];
    const short8_t af1 = *(const short8_t*)&afr[1];

    // --- compute: row rr serves (yy=0,dyi=rr) and (yy=1,dyi=rr-1) ---
#pragma unroll
    for (int rr = 0; rr < 10; ++rr) {
      const int r = 2 * w + rr;
      const short8_t bf0 =
          *(const short8_t*)&sB[half][q * 576 + r * 24 + m];
      const short8_t bf1 =
          *(const short8_t*)&sB[half][q * 576 + r * 24 + 8 + m];
      if (rr <= 8) {
        acc[0][rr][0] = __builtin_amdgcn_mfma_f32_16x16x32_bf16(
            af0, bf0, acc[0][rr][0], 0, 0, 0);
        acc[0][rr][1] = __builtin_amdgcn_mfma_f32_16x16x32_bf16(
            af0, bf1, acc[0][rr][1], 0, 0, 0);
      }
      if (rr >= 1) {
        acc[1][rr - 1][0] = __builtin_amdgcn_mfma_f32_16x16x32_bf16(
            af1, bf0, acc[1][rr - 1][0], 0, 0, 0);
        acc[1][rr - 1][1] = __builtin_amdgcn_mfma_f32_16x16x32_bf16(
            af1, bf1, acc[1][rr - 1][1], 0, 0, 0);
      }
    }
  }

  // --- epilogue: extract diagonals dx = n - m in [0,8], scatter bf16 ---
  // C/D layout: col(n) = lane&15 (=m var), row(mm) = (lane>>4)*4 + reg.
  const float sc = 1.0f / 128.0f;
#pragma unroll
  for (int yy = 0; yy < 2; ++yy) {
    const int y = y0 + 2 * w + yy;
    __hip_bfloat16* dst = a0 + ((size_t)(b * HH + y) * WW + x0) * CINP1;
#pragma unroll
    for (int dyi = 0; dyi < 9; ++dyi) {
#pragma unroll
      for (int t = 0; t < 2; ++t) {
#pragma unroll
        for (int r = 0; r < 4; ++r) {
          const int mm = 4 * q + r;           // output pixel offset
          const int nabs = 8 * t + m;         // absolute x2 column offset
          const int dxi = nabs - mm;
          // t0 covers nabs<16; t1 covers nabs>=16 (dedupe overlap at m<8)
          if (dxi >= 0 && dxi <= 8 && (t == 0 || m >= 8)) {
            dst[(size_t)mm * CINP1 + 128 + dyi * 9 + dxi] =
                __float2bfloat16(acc[yy][dyi][t][r] * sc);
          }
        }
      }
    }
  }
}

// ---------------------------------------------------------------------------
// Weight repack: OIHW fp32 -> bf16 [tap][cout][cin_pad] (zero-pad cin tail).
// ---------------------------------------------------------------------------
__global__ void repack_w_bf16(const float* __restrict__ w,
                              __hip_bfloat16* __restrict__ wt,
                              int COUT, int CIN, int CINPAD) {
  const int idx = blockIdx.x * 256 + threadIdx.x;
  const int n = 9 * COUT * CINPAD;
  if (idx >= n) return;
  const int t = idx / (COUT * CINPAD);
  const int rem = idx - t * (COUT * CINPAD);
  const int co = rem / CINPAD;
  const int ci = rem - co * CINPAD;
  const float v = (ci < CIN) ? w[(size_t)(co * CIN + ci) * 9 + t] : 0.0f;
  wt[idx] = __float2bfloat16(v);
}

// ---------------------------------------------------------------------------
// conv_mfma: implicit-GEMM 3x3 SAME conv, bf16 NHWC in -> bf16 NHWC out.
// Round-1 proven structure: sA + sW staged per cb, 2 barriers/cb, lb(256,2).
// Grid: 1D 896 with the same XCD swizzle as corr_mfma.
// ---------------------------------------------------------------------------
template <int CINPAD, int COUT, bool LEAKY>
__global__ __launch_bounds__(256, 2) void conv_mfma(
    const uint4* __restrict__ inq,          // bf16 NHWC, CINPAD ch/px
    const __hip_bfloat16* __restrict__ wt,  // [9][COUT][CINPAD]
    const float* __restrict__ bias,
    __hip_bfloat16* __restrict__ out) {     // bf16 NHWC, COUT ch/px
  constexpr int NT = COUT / 16;
  constexpr int NCB = CINPAD / 32;
  constexpr int QSTRIDE_A = 324;          // 18*18 px slots per q-plane
  __shared__ uint4 sA[4 * QSTRIDE_A];     // [q][p]
  __shared__ uint4 sW[4 * 9 * COUT];      // [q][t][co]

  const int tid = threadIdx.x;
  const int lane = tid & 63, w = tid >> 6;
  const int m = lane & 15, q = lane >> 4;
  const int lin = blockIdx.x;
  const int b = lin & 7, idx = lin >> 3;
  const int x0 = (idx % 14) * 16, y0 = (idx / 14) * 16;
  const uint4* wq = (const uint4*)wt;

  float4_t acc[4][NT];
#pragma unroll
  for (int my = 0; my < 4; ++my)
#pragma unroll
    for (int nt = 0; nt < NT; ++nt) acc[my][nt] = (float4_t)0.0f;

  for (int cb = 0; cb < NCB; ++cb) {
    __syncthreads();
    // --- stage A halo tile: 18x18 px, chunks cb*4 .. cb*4+3 ---
    for (int s = tid; s < 324; s += 256) {
      const int pr = s / 18, pc = s - pr * 18;
      const int gy = y0 - 1 + pr, gx = x0 - 1 + pc;
      uint4 c0, c1, c2, c3;
      if (gy >= 0 && gy < HH && gx >= 0 && gx < WW) {
        const size_t base =
            ((size_t)(b * HH + gy) * WW + gx) * (CINPAD / 8) + cb * 4;
        c0 = inq[base + 0]; c1 = inq[base + 1];
        c2 = inq[base + 2]; c3 = inq[base + 3];
      } else {
        c0.x=c0.y=c0.z=c0.w=0u; c1=c0; c2=c0; c3=c0;
      }
      sA[0 * QSTRIDE_A + s] = c0;
      sA[1 * QSTRIDE_A + s] = c1;
      sA[2 * QSTRIDE_A + s] = c2;
      sA[3 * QSTRIDE_A + s] = c3;
    }
    // --- stage W chunk: [9][COUT][32ch] ---
    for (int s = tid; s < 9 * COUT; s += 256) {
      const int t = s / COUT, co = s - t * COUT;
      const size_t base = ((size_t)(t * COUT + co) * CINPAD + cb * 32) / 8;
      const uint4 c0 = wq[base + 0], c1 = wq[base + 1];
      const uint4 c2 = wq[base + 2], c3 = wq[base + 3];
      sW[(0 * 9 + t) * COUT + co] = c0;
      sW[(1 * 9 + t) * COUT + co] = c1;
      sW[(2 * 9 + t) * COUT + co] = c2;
      sW[(3 * 9 + t) * COUT + co] = c3;
    }
    __syncthreads();

#pragma unroll
    for (int t = 0; t < 9; ++t) {
      const int tr = t / 3, ds = t % 3;
      short8_t bf[NT];
#pragma unroll
      for (int nt = 0; nt < NT; ++nt) {
        bf[nt] = *(const short8_t*)&sW[(q * 9 + t) * COUT + nt * 16 + m];
      }
#pragma unroll
      for (int my = 0; my < 4; ++my) {
        const int row = 4 * w + my + tr;
        const short8_t af =
            *(const short8_t*)&sA[q * QSTRIDE_A + row * 18 + m + ds];
#pragma unroll
        for (int nt = 0; nt < NT; ++nt) {
          acc[my][nt] = __builtin_amdgcn_mfma_f32_16x16x32_bf16(
              af, bf[nt], acc[my][nt], 0, 0, 0);
        }
      }
    }
  }

  // --- epilogue: bias + leaky + bf16 NHWC store ---
  // C/D layout: col(n)=lane&15, row(m)=(lane>>4)*4+r
#pragma unroll
  for (int my = 0; my < 4; ++my) {
    const int y = y0 + 4 * w + my;
#pragma unroll
    for (int nt = 0; nt < NT; ++nt) {
      const int co = nt * 16 + m;
      const float bv = bias[co];
#pragma unroll
      for (int r = 0; r < 4; ++r) {
        const int x = x0 + q * 4 + r;
        float v = acc[my][nt][r] + bv;
        if (LEAKY) v = (v >= 0.0f) ? v : 0.1f * v;
        out[((size_t)(b * HH + y) * WW + x) * COUT + co] = __float2bfloat16(v);
      }
    }
  }
}

// ---------------------------------------------------------------------------
// conv4: 32 -> 2, direct, bf16 NHWC in -> fp32 NCHW out (final flow).
// ---------------------------------------------------------------------------
__global__ __launch_bounds__(256, 2) void conv4_kernel(
    const uint4* __restrict__ inq,          // h3, 32ch/px = 4 uint4
    const __hip_bfloat16* __restrict__ wt,  // [9][2][32]
    const float* __restrict__ bias,
    float* __restrict__ out) {
  __shared__ uint4 sA[4 * 324];
  __shared__ uint4 sW[9 * 2 * 4];  // [t][co][q]
  const int tid = threadIdx.x;
  const int tx = tid & 15, ty = tid >> 4;
  const int x0 = blockIdx.x * 16, y0 = blockIdx.y * 16, b = blockIdx.z;

  for (int s = tid; s < 324; s += 256) {
    const int pr = s / 18, pc = s - pr * 18;
    const int gy = y0 - 1 + pr, gx = x0 - 1 + pc;
    uint4 c0, c1, c2, c3;
    if (gy >= 0 && gy < HH && gx >= 0 && gx < WW) {
      const size_t base = ((size_t)(b * HH + gy) * WW + gx) * 4;
      c0 = inq[base + 0]; c1 = inq[base + 1];
      c2 = inq[base + 2]; c3 = inq[base + 3];
    } else {
      c0.x=c0.y=c0.z=c0.w=0u; c1=c0; c2=c0; c3=c0;
    }
    sA[0 * 324 + s] = c0; sA[1 * 324 + s] = c1;
    sA[2 * 324 + s] = c2; sA[3 * 324 + s] = c3;
  }
  if (tid < 72) sW[tid] = ((const uint4*)wt)[tid];
  __syncthreads();

  float acc0 = bias[0], acc1 = bias[1];
#pragma unroll
  for (int t = 0; t < 9; ++t) {
    const int dy = t / 3 - 1, dx = t % 3 - 1;
    const int row = ty + dy + 1, col = tx + dx + 1;
#pragma unroll
    for (int qi = 0; qi < 4; ++qi) {
      const short8_t a = *(const short8_t*)&sA[qi * 324 + row * 18 + col];
      const short8_t w0 = *(const short8_t*)&sW[(t * 2 + 0) * 4 + qi];
      const short8_t w1 = *(const short8_t*)&sW[(t * 2 + 1) * 4 + qi];
#pragma unroll
      for (int j = 0; j < 8; ++j) {
        const float av = bf2f(a[j]);
        acc0 += av * bf2f(w0[j]);
        acc1 += av * bf2f(w1[j]);
      }
    }
  }
  const int y = y0 + ty, x = x0 + tx;
  out[((size_t)(b * 2 + 0) * HH + y) * WW + x] = acc0;
  out[((size_t)(b * 2 + 1) * HH + y) * WW + x] = acc1;
}

// ---------------------------------------------------------------------------
// Launch
// ---------------------------------------------------------------------------
extern "C" void kernel_launch(void* const* d_in, const int* in_sizes, int n_in,
                              void* d_out, int out_size, void* d_ws,
                              size_t ws_size, hipStream_t stream) {
  const float* x1 = (const float*)d_in[0];
  const float* x2 = (const float*)d_in[1];
  const float* w1 = (const float*)d_in[2];
  const float* b1 = (const float*)d_in[3];
  const float* w2 = (const float*)d_in[4];
  const float* b2 = (const float*)d_in[5];
  const float* w3 = (const float*)d_in[6];
  const float* b3 = (const float*)d_in[7];
  const float* w4 = (const float*)d_in[8];
  const float* b4 = (const float*)d_in[9];
  float* out = (float*)d_out;

  // Workspace (bytes):
  //  A0   [0, 102760448)             bf16 NHWC 224ch concat (x1+corr+pad)
  //  h1   [102760448, +29360128)     bf16 NHWC 64ch
  //  wt1..wt4                        bf16 repacked weights (~370 KB)
  //  X2n  (optional, +58720256)      bf16 x2 planes [16][B*H*W] uint4
  //  h2 reuses A0[0, 29360128); h3 reuses A0[29360128, 44040192)
  char* ws = (char*)d_ws;
  __hip_bfloat16* A0 = (__hip_bfloat16*)ws;
  const size_t A0_BYTES = (size_t)BN * HH * WW * CINP1 * 2;  // 102,760,448
  __hip_bfloat16* h1 = (__hip_bfloat16*)(ws + A0_BYTES);
  const size_t H1_BYTES = (size_t)BN * HH * WW * 64 * 2;     // 29,360,128
  __hip_bfloat16* wt1 = (__hip_bfloat16*)(ws + A0_BYTES + H1_BYTES);
  __hip_bfloat16* wt2 = wt1 + 9 * 64 * CINP1;
  __hip_bfloat16* wt3 = wt2 + 9 * 64 * 64;
  __hip_bfloat16* wt4 = wt3 + 9 * 32 * 64;
  const size_t WT_BYTES = 2 * (9 * 64 * CINP1 + 9 * 64 * 64 + 9 * 32 * 64 +
                               9 * 2 * 32);
  // X2n plane buffer, 256B aligned, only if the workspace is big enough
  const size_t x2n_off = (A0_BYTES + H1_BYTES + WT_BYTES + 255) & ~(size_t)255;
  const size_t X2N_BYTES = (size_t)BN * HH * WW * CCH * 2;   // 58,720,256
  const int preconv = (ws_size >= x2n_off + X2N_BYTES) ? 1 : 0;
  __hip_bfloat16* h2 = (__hip_bfloat16*)ws;
  __hip_bfloat16* h3 = (__hip_bfloat16*)(ws + H1_BYTES);

  // weight repacks (tiny)
  {
    int n1 = 9 * 64 * CINP1;
    repack_w_bf16<<<(n1 + 255) / 256, 256, 0, stream>>>(w1, wt1, 64, 209, CINP1);
    int n2 = 9 * 64 * 64;
    repack_w_bf16<<<(n2 + 255) / 256, 256, 0, stream>>>(w2, wt2, 64, 64, 64);
    int n3 = 9 * 32 * 64;
    repack_w_bf16<<<(n3 + 255) / 256, 256, 0, stream>>>(w3, wt3, 32, 64, 64);
    int n4 = 9 * 2 * 32;
    repack_w_bf16<<<(n4 + 255) / 256, 256, 0, stream>>>(w4, wt4, 2, 32, 32);
  }

  // x1 -> A0 (bf16 NHWC) + zero pad channels; LDS-transpose, 64 px/block
  convert_x1<<<BN * HH * WW / 64, 256, 0, stream>>>(x1, (uint4*)A0);

  // correlation -> A0 channels 128..208 (banded MFMA GEMM, XCD-swizzled)
  const uint4* x2q = (const uint4*)(ws + x2n_off);
  if (preconv) {
    convert_x2<<<dim3(BN * HH * WW / 256, 16), 256, 0, stream>>>(
        x2, (uint4*)x2q);
  } else {
    x2q = (const uint4*)A0;  // unused by the !preconv path; valid pointer
  }
  corr_mfma<<<896, 512, 0, stream>>>(x2, x2q, (const uint4*)A0, A0, preconv);

  conv_mfma<CINP1, 64, true>
      <<<896, 256, 0, stream>>>((const uint4*)A0, wt1, b1, h1);
  conv_mfma<64, 64, true>
      <<<896, 256, 0, stream>>>((const uint4*)h1, wt2, b2, h2);
  conv_mfma<64, 32, true>
      <<<896, 256, 0, stream>>>((const uint4*)h2, wt3, b3, h3);
  const dim3 grid(WW / 16, HH / 16, BN);  // 14 x 8 x 8
  conv4_kernel<<<grid, 256, 0, stream>>>((const uint4*)h3, wt4, b4, out);
}

// Round 10
// 485.041 us; speedup vs baseline: 1.0594x; 1.0594x over previous
//
#include <hip/hip_runtime.h>
#include <hip/hip_bf16.h>
#include <cstddef>

// Problem constants (LiteFlowNetCorr): B=8, C=128, H=128, W=224, R=4
#define BN 8
#define CCH 128
#define HH 128
#define WW 224
#define ND 81            // (2R+1)^2 displacements
#define CINP1 224        // conv1 K padded: 128 (x1) + 81 (corr) + 15 zeros

typedef __attribute__((ext_vector_type(8))) short short8_t;   // 8 bf16
typedef __attribute__((ext_vector_type(4))) float float4_t;   // MFMA acc

static __device__ __forceinline__ unsigned short f2bf(float f) {
  __hip_bfloat16 h = __float2bfloat16(f);
  return *(unsigned short*)&h;
}
static __device__ __forceinline__ float bf2f(short s) {
  unsigned u = ((unsigned)(unsigned short)s) << 16;
  return __uint_as_float(u);
}

// ---------------------------------------------------------------------------
// convert_x1 (v3, LDS transpose): x1 fp32 NCHW -> A0 bf16 NHWC.
// Block = 64 px x 128 ch; float4 pixel-major loads -> LDS stride 65 ->
// uint4 chunk stores. Chunks 26,27 zeroed.
// ---------------------------------------------------------------------------
__global__ __launch_bounds__(256) void convert_x1(
    const float* __restrict__ x1, uint4* __restrict__ a0q) {
  __shared__ unsigned sT[64 * 65];  // [px][cp], stride 65 dwords
  const int tid = threadIdx.x;
  const int g0 = blockIdx.x * 64;   // 64 | hw, tiles never cross batch
  const int hw = HH * WW;
  const int b = g0 / hw, px0 = g0 - b * hw;
  const float* src = x1 + (size_t)b * CCH * hw + px0;

#pragma unroll
  for (int it = 0; it < 4; ++it) {
    const int s = it * 256 + tid;
    const int pg4 = s & 15, cp = s >> 4;   // cp = channel pair 0..63
    const float4 a = *(const float4*)&src[(size_t)(2 * cp) * hw + 4 * pg4];
    const float4 c = *(const float4*)&src[(size_t)(2 * cp + 1) * hw + 4 * pg4];
    const float av[4] = {a.x, a.y, a.z, a.w};
    const float cv[4] = {c.x, c.y, c.z, c.w};
#pragma unroll
    for (int j = 0; j < 4; ++j) {
      sT[(4 * pg4 + j) * 65 + cp] =
          (unsigned)f2bf(av[j]) | ((unsigned)f2bf(cv[j]) << 16);
    }
  }
  __syncthreads();

#pragma unroll
  for (int it = 0; it < 4; ++it) {
    const int s = it * 256 + tid;
    const int chunk = s & 15, px = s >> 4;
    uint4 u;
    u.x = sT[px * 65 + 4 * chunk + 0];
    u.y = sT[px * 65 + 4 * chunk + 1];
    u.z = sT[px * 65 + 4 * chunk + 2];
    u.w = sT[px * 65 + 4 * chunk + 3];
    a0q[(size_t)(g0 + px) * 28 + chunk] = u;
  }
  if (tid < 128) {
    const int px = tid >> 1, ch = 26 + (tid & 1);
    uint4 z; z.x = z.y = z.z = z.w = 0u;
    a0q[(size_t)(g0 + px) * 28 + ch] = z;
  }
}

// ---------------------------------------------------------------------------
// convert_x2 (v3, LDS transpose): x2 fp32 NCHW -> bf16 planes
// [16 planes][B*H*W] of uint4; plane p holds channels p*8..p*8+7.
// ---------------------------------------------------------------------------
__global__ __launch_bounds__(256) void convert_x2(
    const float* __restrict__ x2, uint4* __restrict__ x2q) {
  __shared__ unsigned sT[256 * 5];  // [px][cp], stride 5 dwords
  const int tid = threadIdx.x;
  const int p = blockIdx.y;                      // plane 0..15
  const int g0 = blockIdx.x * 256;               // 256 | hw
  const int hw = HH * WW;
  const int b = g0 / hw, px0 = g0 - b * hw;
  const float* src = x2 + ((size_t)b * CCH + p * 8) * hw + px0;

  const int cp = tid & 3, pg4 = tid >> 2;        // pg4 = 0..63
  const float4 a = *(const float4*)&src[(size_t)(2 * cp) * hw + 4 * pg4];
  const float4 c = *(const float4*)&src[(size_t)(2 * cp + 1) * hw + 4 * pg4];
  const float av[4] = {a.x, a.y, a.z, a.w};
  const float cv[4] = {c.x, c.y, c.z, c.w};
#pragma unroll
  for (int j = 0; j < 4; ++j) {
    sT[(4 * pg4 + j) * 5 + cp] =
        (unsigned)f2bf(av[j]) | ((unsigned)f2bf(cv[j]) << 16);
  }
  __syncthreads();

  uint4 u;
  u.x = sT[tid * 5 + 0];
  u.y = sT[tid * 5 + 1];
  u.z = sT[tid * 5 + 2];
  u.w = sT[tid * 5 + 3];
  x2q[(size_t)p * (BN * hw) + g0 + tid] = u;
}

// ---------------------------------------------------------------------------
// corr_mfma (v4, double-buffered sB): correlation as banded implicit GEMM.
// 83 us, neutral vs v3 (structure ceiling; m99/m100 pattern). Unchanged.
// ---------------------------------------------------------------------------
__global__ __launch_bounds__(512, 2) void corr_mfma(
    const float* __restrict__ x2,
    const uint4* __restrict__ x2q,          // bf16 planes (may alias A0)
    const uint4* __restrict__ a0q,          // x1 bf16 NHWC = chunks 0..15
    __hip_bfloat16* __restrict__ a0,        // corr out: channels 128..208
    int use_preconv) {
  __shared__ uint4 sB[2][4 * 576];  // [half][q][r*24+c]
  const int tid = threadIdx.x;
  const int lane = tid & 63, w = tid >> 6;   // 8 waves
  const int m = lane & 15, q = lane >> 4;    // MFMA operand lane split
  // XCD swizzle: 896 blocks = 8 xcd chunks of 112; batch = xcd.
  const int lin = blockIdx.x;
  const int b = lin & 7, idx = lin >> 3;
  const int x0 = (idx % 14) * 16, y0 = (idx / 14) * 16;
  const int hw = HH * WW;

  float4_t acc[2][9][2];
#pragma unroll
  for (int yy = 0; yy < 2; ++yy)
#pragma unroll
    for (int d = 0; d < 9; ++d)
#pragma unroll
      for (int t = 0; t < 2; ++t) acc[yy][d][t] = (float4_t)0.0f;

  auto stage = [&](int cb, int half) {
    for (int s = tid; s < 2304; s += 512) {
      const int qs = s / 576, rc = s - qs * 576;
      const int r = rc / 24, c = rc - r * 24;
      const int gy = y0 - 4 + r, gx = x0 - 4 + c;
      uint4 u; u.x = u.y = u.z = u.w = 0u;
      if (gy >= 0 && gy < HH && gx >= 0 && gx < WW) {
        if (use_preconv) {
          u = x2q[(size_t)(cb * 4 + qs) * (BN * hw) +
                  (size_t)(b * HH + gy) * WW + gx];
        } else {
          const float* p2 =
              x2 + (size_t)(b * CCH + cb * 32 + qs * 8) * hw + gy * WW + gx;
          unsigned rr[4];
#pragma unroll
          for (int j = 0; j < 4; ++j) {
            const float f0 = p2[(size_t)(2 * j + 0) * hw];
            const float f1 = p2[(size_t)(2 * j + 1) * hw];
            rr[j] = (unsigned)f2bf(f0) | ((unsigned)f2bf(f1) << 16);
          }
          u.x = rr[0]; u.y = rr[1]; u.z = rr[2]; u.w = rr[3];
        }
      }
      sB[half][s] = u;
    }
  };

  stage(0, 0);
  for (int cb = 0; cb < 4; ++cb) {  // 4 blocks of 32 channels
    __syncthreads();                 // half (cb&1) staged; prev reads done
    if (cb + 1 < 4) stage(cb + 1, (cb + 1) & 1);
    const int half = cb & 1;

    // --- A-fragments: this wave's two x1 rows, from A0 (bf16 NHWC) ---
    uint4 afr[2];
#pragma unroll
    for (int yy = 0; yy < 2; ++yy) {
      const int y = y0 + 2 * w + yy;
      afr[yy] = a0q[((size_t)(b * HH + y) * WW + x0 + m) * 28 + cb * 4 + q];
    }
    const short8_t af0 = *(const short8_t*)&afr[0];
    const short8_t af1 = *(const short8_t*)&afr[1];

    // --- compute: row rr serves (yy=0,dyi=rr) and (yy=1,dyi=rr-1) ---
#pragma unroll
    for (int rr = 0; rr < 10; ++rr) {
      const int r = 2 * w + rr;
      const short8_t bf0 =
          *(const short8_t*)&sB[half][q * 576 + r * 24 + m];
      const short8_t bf1 =
          *(const short8_t*)&sB[half][q * 576 + r * 24 + 8 + m];
      if (rr <= 8) {
        acc[0][rr][0] = __builtin_amdgcn_mfma_f32_16x16x32_bf16(
            af0, bf0, acc[0][rr][0], 0, 0, 0);
        acc[0][rr][1] = __builtin_amdgcn_mfma_f32_16x16x32_bf16(
            af0, bf1, acc[0][rr][1], 0, 0, 0);
      }
      if (rr >= 1) {
        acc[1][rr - 1][0] = __builtin_amdgcn_mfma_f32_16x16x32_bf16(
            af1, bf0, acc[1][rr - 1][0], 0, 0, 0);
        acc[1][rr - 1][1] = __builtin_amdgcn_mfma_f32_16x16x32_bf16(
            af1, bf1, acc[1][rr - 1][1], 0, 0, 0);
      }
    }
  }

  // --- epilogue: extract diagonals dx = n - m in [0,8], scatter bf16 ---
  // C/D layout: col(n) = lane&15 (=m var), row(mm) = (lane>>4)*4 + reg.
  const float sc = 1.0f / 128.0f;
#pragma unroll
  for (int yy = 0; yy < 2; ++yy) {
    const int y = y0 + 2 * w + yy;
    __hip_bfloat16* dst = a0 + ((size_t)(b * HH + y) * WW + x0) * CINP1;
#pragma unroll
    for (int dyi = 0; dyi < 9; ++dyi) {
#pragma unroll
      for (int t = 0; t < 2; ++t) {
#pragma unroll
        for (int r = 0; r < 4; ++r) {
          const int mm = 4 * q + r;           // output pixel offset
          const int nabs = 8 * t + m;         // absolute x2 column offset
          const int dxi = nabs - mm;
          // t0 covers nabs<16; t1 covers nabs>=16 (dedupe overlap at m<8)
          if (dxi >= 0 && dxi <= 8 && (t == 0 || m >= 8)) {
            dst[(size_t)mm * CINP1 + 128 + dyi * 9 + dxi] =
                __float2bfloat16(acc[yy][dyi][t][r] * sc);
          }
        }
      }
    }
  }
}

// ---------------------------------------------------------------------------
// Weight repack: OIHW fp32 -> bf16 [tap][cout][cin_pad] (zero-pad cin tail).
// ---------------------------------------------------------------------------
__global__ void repack_w_bf16(const float* __restrict__ w,
                              __hip_bfloat16* __restrict__ wt,
                              int COUT, int CIN, int CINPAD) {
  const int idx = blockIdx.x * 256 + threadIdx.x;
  const int n = 9 * COUT * CINPAD;
  if (idx >= n) return;
  const int t = idx / (COUT * CINPAD);
  const int rem = idx - t * (COUT * CINPAD);
  const int co = rem / CINPAD;
  const int ci = rem - co * CINPAD;
  const float v = (ci < CIN) ? w[(size_t)(co * CIN + ci) * 9 + t] : 0.0f;
  wt[idx] = __float2bfloat16(v);
}

// ---------------------------------------------------------------------------
// conv_mfma (v4, 32-row tile): implicit-GEMM 3x3 SAME conv, bf16 NHWC.
// Block: 512 thr = 8 waves; out tile 32 rows x 16 cols; wave w owns rows
// 4w..4w+3. Grid 448 (14 x-tiles x 4 y-tiles x 8 batches), XCD swizzle.
// vs v1 (16-row, 256 thr): half the barrier phases per output, half the
// sW staging per output, 16 waves/CU (4/SIMD) instead of 8 -> latency
// hiding. LDS: sA 4x612x16 = 39.2 KB + sW 36.9 KB (COUT=64) = 76 KB ->
// 2 blocks/CU. lb(512,4) caps VGPR at 128 (acc 64 + addr ~88 fits).
// ---------------------------------------------------------------------------
template <int CINPAD, int COUT, bool LEAKY>
__global__ __launch_bounds__(512, 4) void conv_mfma(
    const uint4* __restrict__ inq,          // bf16 NHWC, CINPAD ch/px
    const __hip_bfloat16* __restrict__ wt,  // [9][COUT][CINPAD]
    const float* __restrict__ bias,
    __hip_bfloat16* __restrict__ out) {     // bf16 NHWC, COUT ch/px
  constexpr int NT = COUT / 16;
  constexpr int NCB = CINPAD / 32;
  constexpr int QSTRIDE_A = 34 * 18;      // 612 px slots per q-plane
  __shared__ uint4 sA[4 * QSTRIDE_A];     // [q][p]
  __shared__ uint4 sW[4 * 9 * COUT];      // [q][t][co]

  const int tid = threadIdx.x;
  const int lane = tid & 63, w = tid >> 6;   // 8 waves
  const int m = lane & 15, q = lane >> 4;
  const int lin = blockIdx.x;                // 448 blocks
  const int b = lin & 7, idx = lin >> 3;
  const int x0 = (idx % 14) * 16, y0 = (idx / 14) * 32;
  const uint4* wq = (const uint4*)wt;

  float4_t acc[4][NT];
#pragma unroll
  for (int my = 0; my < 4; ++my)
#pragma unroll
    for (int nt = 0; nt < NT; ++nt) acc[my][nt] = (float4_t)0.0f;

  for (int cb = 0; cb < NCB; ++cb) {
    __syncthreads();
    // --- stage A halo tile: 34x18 px, chunks cb*4 .. cb*4+3 ---
    for (int s = tid; s < QSTRIDE_A; s += 512) {
      const int pr = s / 18, pc = s - pr * 18;
      const int gy = y0 - 1 + pr, gx = x0 - 1 + pc;
      uint4 c0, c1, c2, c3;
      if (gy >= 0 && gy < HH && gx >= 0 && gx < WW) {
        const size_t base =
            ((size_t)(b * HH + gy) * WW + gx) * (CINPAD / 8) + cb * 4;
        c0 = inq[base + 0]; c1 = inq[base + 1];
        c2 = inq[base + 2]; c3 = inq[base + 3];
      } else {
        c0.x=c0.y=c0.z=c0.w=0u; c1=c0; c2=c0; c3=c0;
      }
      sA[0 * QSTRIDE_A + s] = c0;
      sA[1 * QSTRIDE_A + s] = c1;
      sA[2 * QSTRIDE_A + s] = c2;
      sA[3 * QSTRIDE_A + s] = c3;
    }
    // --- stage W chunk: [9][COUT][32ch] ---
    for (int s = tid; s < 9 * COUT; s += 512) {
      const int t = s / COUT, co = s - t * COUT;
      const size_t base = ((size_t)(t * COUT + co) * CINPAD + cb * 32) / 8;
      const uint4 c0 = wq[base + 0], c1 = wq[base + 1];
      const uint4 c2 = wq[base + 2], c3 = wq[base + 3];
      sW[(0 * 9 + t) * COUT + co] = c0;
      sW[(1 * 9 + t) * COUT + co] = c1;
      sW[(2 * 9 + t) * COUT + co] = c2;
      sW[(3 * 9 + t) * COUT + co] = c3;
    }
    __syncthreads();

#pragma unroll
    for (int t = 0; t < 9; ++t) {
      const int tr = t / 3, ds = t % 3;
      short8_t bf[NT];
#pragma unroll
      for (int nt = 0; nt < NT; ++nt) {
        bf[nt] = *(const short8_t*)&sW[(q * 9 + t) * COUT + nt * 16 + m];
      }
#pragma unroll
      for (int my = 0; my < 4; ++my) {
        const int row = 4 * w + my + tr;
        const short8_t af =
            *(const short8_t*)&sA[q * QSTRIDE_A + row * 18 + m + ds];
#pragma unroll
        for (int nt = 0; nt < NT; ++nt) {
          acc[my][nt] = __builtin_amdgcn_mfma_f32_16x16x32_bf16(
              af, bf[nt], acc[my][nt], 0, 0, 0);
        }
      }
    }
  }

  // --- epilogue: bias + leaky + bf16 NHWC store ---
  // C/D layout: col(n)=lane&15, row(m)=(lane>>4)*4+r
#pragma unroll
  for (int my = 0; my < 4; ++my) {
    const int y = y0 + 4 * w + my;
#pragma unroll
    for (int nt = 0; nt < NT; ++nt) {
      const int co = nt * 16 + m;
      const float bv = bias[co];
#pragma unroll
      for (int r = 0; r < 4; ++r) {
        const int x = x0 + q * 4 + r;
        float v = acc[my][nt][r] + bv;
        if (LEAKY) v = (v >= 0.0f) ? v : 0.1f * v;
        out[((size_t)(b * HH + y) * WW + x) * COUT + co] = __float2bfloat16(v);
      }
    }
  }
}

// ---------------------------------------------------------------------------
// conv4: 32 -> 2, direct, bf16 NHWC in -> fp32 NCHW out (final flow).
// ---------------------------------------------------------------------------
__global__ __launch_bounds__(256, 2) void conv4_kernel(
    const uint4* __restrict__ inq,          // h3, 32ch/px = 4 uint4
    const __hip_bfloat16* __restrict__ wt,  // [9][2][32]
    const float* __restrict__ bias,
    float* __restrict__ out) {
  __shared__ uint4 sA[4 * 324];
  __shared__ uint4 sW[9 * 2 * 4];  // [t][co][q]
  const int tid = threadIdx.x;
  const int tx = tid & 15, ty = tid >> 4;
  const int x0 = blockIdx.x * 16, y0 = blockIdx.y * 16, b = blockIdx.z;

  for (int s = tid; s < 324; s += 256) {
    const int pr = s / 18, pc = s - pr * 18;
    const int gy = y0 - 1 + pr, gx = x0 - 1 + pc;
    uint4 c0, c1, c2, c3;
    if (gy >= 0 && gy < HH && gx >= 0 && gx < WW) {
      const size_t base = ((size_t)(b * HH + gy) * WW + gx) * 4;
      c0 = inq[base + 0]; c1 = inq[base + 1];
      c2 = inq[base + 2]; c3 = inq[base + 3];
    } else {
      c0.x=c0.y=c0.z=c0.w=0u; c1=c0; c2=c0; c3=c0;
    }
    sA[0 * 324 + s] = c0; sA[1 * 324 + s] = c1;
    sA[2 * 324 + s] = c2; sA[3 * 324 + s] = c3;
  }
  if (tid < 72) sW[tid] = ((const uint4*)wt)[tid];
  __syncthreads();

  float acc0 = bias[0], acc1 = bias[1];
#pragma unroll
  for (int t = 0; t < 9; ++t) {
    const int dy = t / 3 - 1, dx = t % 3 - 1;
    const int row = ty + dy + 1, col = tx + dx + 1;
#pragma unroll
    for (int qi = 0; qi < 4; ++qi) {
      const short8_t a = *(const short8_t*)&sA[qi * 324 + row * 18 + col];
      const short8_t w0 = *(const short8_t*)&sW[(t * 2 + 0) * 4 + qi];
      const short8_t w1 = *(const short8_t*)&sW[(t * 2 + 1) * 4 + qi];
#pragma unroll
      for (int j = 0; j < 8; ++j) {
        const float av = bf2f(a[j]);
        acc0 += av * bf2f(w0[j]);
        acc1 += av * bf2f(w1[j]);
      }
    }
  }
  const int y = y0 + ty, x = x0 + tx;
  out[((size_t)(b * 2 + 0) * HH + y) * WW + x] = acc0;
  out[((size_t)(b * 2 + 1) * HH + y) * WW + x] = acc1;
}

// ---------------------------------------------------------------------------
// Launch
// ---------------------------------------------------------------------------
extern "C" void kernel_launch(void* const* d_in, const int* in_sizes, int n_in,
                              void* d_out, int out_size, void* d_ws,
                              size_t ws_size, hipStream_t stream) {
  const float* x1 = (const float*)d_in[0];
  const float* x2 = (const float*)d_in[1];
  const float* w1 = (const float*)d_in[2];
  const float* b1 = (const float*)d_in[3];
  const float* w2 = (const float*)d_in[4];
  const float* b2 = (const float*)d_in[5];
  const float* w3 = (const float*)d_in[6];
  const float* b3 = (const float*)d_in[7];
  const float* w4 = (const float*)d_in[8];
  const float* b4 = (const float*)d_in[9];
  float* out = (float*)d_out;

  // Workspace (bytes):
  //  A0   [0, 102760448)             bf16 NHWC 224ch concat (x1+corr+pad)
  //  h1   [102760448, +29360128)     bf16 NHWC 64ch
  //  wt1..wt4                        bf16 repacked weights (~370 KB)
  //  X2n  (optional, +58720256)      bf16 x2 planes [16][B*H*W] uint4
  //  h2 reuses A0[0, 29360128); h3 reuses A0[29360128, 44040192)
  char* ws = (char*)d_ws;
  __hip_bfloat16* A0 = (__hip_bfloat16*)ws;
  const size_t A0_BYTES = (size_t)BN * HH * WW * CINP1 * 2;  // 102,760,448
  __hip_bfloat16* h1 = (__hip_bfloat16*)(ws + A0_BYTES);
  const size_t H1_BYTES = (size_t)BN * HH * WW * 64 * 2;     // 29,360,128
  __hip_bfloat16* wt1 = (__hip_bfloat16*)(ws + A0_BYTES + H1_BYTES);
  __hip_bfloat16* wt2 = wt1 + 9 * 64 * CINP1;
  __hip_bfloat16* wt3 = wt2 + 9 * 64 * 64;
  __hip_bfloat16* wt4 = wt3 + 9 * 32 * 64;
  const size_t WT_BYTES = 2 * (9 * 64 * CINP1 + 9 * 64 * 64 + 9 * 32 * 64 +
                               9 * 2 * 32);
  // X2n plane buffer, 256B aligned, only if the workspace is big enough
  const size_t x2n_off = (A0_BYTES + H1_BYTES + WT_BYTES + 255) & ~(size_t)255;
  const size_t X2N_BYTES = (size_t)BN * HH * WW * CCH * 2;   // 58,720,256
  const int preconv = (ws_size >= x2n_off + X2N_BYTES) ? 1 : 0;
  __hip_bfloat16* h2 = (__hip_bfloat16*)ws;
  __hip_bfloat16* h3 = (__hip_bfloat16*)(ws + H1_BYTES);

  // weight repacks (tiny)
  {
    int n1 = 9 * 64 * CINP1;
    repack_w_bf16<<<(n1 + 255) / 256, 256, 0, stream>>>(w1, wt1, 64, 209, CINP1);
    int n2 = 9 * 64 * 64;
    repack_w_bf16<<<(n2 + 255) / 256, 256, 0, stream>>>(w2, wt2, 64, 64, 64);
    int n3 = 9 * 32 * 64;
    repack_w_bf16<<<(n3 + 255) / 256, 256, 0, stream>>>(w3, wt3, 32, 64, 64);
    int n4 = 9 * 2 * 32;
    repack_w_bf16<<<(n4 + 255) / 256, 256, 0, stream>>>(w4, wt4, 2, 32, 32);
  }

  // x1 -> A0 (bf16 NHWC) + zero pad channels; LDS-transpose, 64 px/block
  convert_x1<<<BN * HH * WW / 64, 256, 0, stream>>>(x1, (uint4*)A0);

  // correlation -> A0 channels 128..208 (banded MFMA GEMM, XCD-swizzled)
  const uint4* x2q = (const uint4*)(ws + x2n_off);
  if (preconv) {
    convert_x2<<<dim3(BN * HH * WW / 256, 16), 256, 0, stream>>>(
        x2, (uint4*)x2q);
  } else {
    x2q = (const uint4*)A0;  // unused by the !preconv path; valid pointer
  }
  corr_mfma<<<896, 512, 0, stream>>>(x2, x2q, (const uint4*)A0, A0, preconv);

  // convs: 32-row tiles, 448 blocks (14 x-tiles x 4 y-tiles x 8 batches)
  conv_mfma<CINP1, 64, true>
      <<<448, 512, 0, stream>>>((const uint4*)A0, wt1, b1, h1);
  conv_mfma<64, 64, true>
      <<<448, 512, 0, stream>>>((const uint4*)h1, wt2, b2, h2);
  conv_mfma<64, 32, true>
      <<<448, 512, 0, stream>>>((const uint4*)h2, wt3, b3, h3);
  const dim3 grid(WW / 16, HH / 16, BN);  // 14 x 8 x 8
  conv4_kernel<<<grid, 256, 0, stream>>>((const uint4*)h3, wt4, b4, out);
}